// Round 4
// baseline (440.436 us; speedup 1.0000x reference)
//
#include <hip/hip_runtime.h>

#define D 128
#define GTM 32
#define SCAN_ELEMS 4096   // elements per scan block (256 threads x 16)

// ---------------- precompute kernels ----------------
// deg[] counts REAL edges only (self-loop handled as +1 at use sites).

__global__ void count_kernel(const int* __restrict__ dst, int* __restrict__ deg, int e) {
    int i = blockIdx.x * blockDim.x + threadIdx.x;
    if (i < e) atomicAdd(&deg[dst[i]], 1);
}

// ---- hierarchical scan: A) block sums  B) scan block sums  C) final offsets + dinv ----

__global__ __launch_bounds__(256) void scanA_kernel(const int* __restrict__ deg,
                                                    int* __restrict__ blkSums, int n) {
    __shared__ int waveSums[4];
    int t = threadIdx.x;
    int base = blockIdx.x * SCAN_ELEMS + t * 16;
    int s = 0;
    if (base + 16 <= n) {
        const int4* p = reinterpret_cast<const int4*>(deg + base);
        #pragma unroll
        for (int k = 0; k < 4; ++k) {
            int4 v = p[k];
            s += v.x + v.y + v.z + v.w;
        }
    } else {
        for (int k = 0; k < 16; ++k) {
            int i = base + k;
            if (i < n) s += deg[i];
        }
    }
    #pragma unroll
    for (int off = 32; off > 0; off >>= 1) s += __shfl_down(s, off);
    int lane = t & 63, w = t >> 6;
    if (lane == 0) waveSums[w] = s;
    __syncthreads();
    if (t == 0) blkSums[blockIdx.x] = waveSums[0] + waveSums[1] + waveSums[2] + waveSums[3];
}

__global__ void scanB_kernel(const int* __restrict__ blkSums, int* __restrict__ blkOff, int nblk) {
    int t = threadIdx.x;   // 64 threads
    int s = (t < nblk) ? blkSums[t] : 0;
    int orig = s;
    #pragma unroll
    for (int off = 1; off < 64; off <<= 1) {
        int u = __shfl_up(s, off);
        if (t >= off) s += u;
    }
    if (t < nblk) blkOff[t] = s - orig;   // exclusive
}

__global__ __launch_bounds__(256) void scanC_kernel(const int* __restrict__ deg,
                                                    const int* __restrict__ blkOff,
                                                    int* __restrict__ offsets,
                                                    float* __restrict__ dinv, int n) {
    __shared__ int waveSums[4];
    int t = threadIdx.x;
    int lane = t & 63, w = t >> 6;
    int base = blockIdx.x * SCAN_ELEMS + t * 16;

    int v[16];
    int s = 0;
    #pragma unroll
    for (int k = 0; k < 16; ++k) {
        int i = base + k;
        int d = (i < n) ? deg[i] : 0;
        v[k] = d;
        s += d;
    }
    int incl = s;
    #pragma unroll
    for (int off = 1; off < 64; off <<= 1) {
        int u = __shfl_up(incl, off);
        if (lane >= off) incl += u;
    }
    if (lane == 63) waveSums[w] = incl;
    __syncthreads();
    int waveOff = 0;
    for (int i = 0; i < 4; ++i) if (i < w) waveOff += waveSums[i];
    int off0 = blkOff[blockIdx.x] + waveOff + incl - s;

    #pragma unroll
    for (int k = 0; k < 16; ++k) {
        int i = base + k;
        if (i < n) {
            offsets[i] = off0;
            dinv[i] = rsqrtf((float)(v[k] + 1));   // +1 self-loop
            off0 += v[k];
        }
    }
}

__global__ void fill_kernel(const int* __restrict__ src, const int* __restrict__ dst,
                            const int* __restrict__ offsets, int* __restrict__ cursor,
                            int* __restrict__ csr_src, int e) {
    int i = blockIdx.x * blockDim.x + threadIdx.x;
    if (i < e) {
        int d = dst[i];
        int pos = offsets[d] + atomicAdd(&cursor[d], 1);
        csr_src[pos] = src[i];
    }
}

// ---------------- dense transform: out[r][c] = dinv[r] * (A[r][:] @ W[:][c]) ----------------
__global__ __launch_bounds__(64, 2) void gemm_kernel(const float* __restrict__ A,
                                                     const float* __restrict__ Wg,
                                                     const float* __restrict__ dinv,
                                                     float* __restrict__ outp, int n) {
    __shared__ float AsT[32][36];   // [k][row]
    __shared__ float Ws[32][132];   // [k][col]

    int t = threadIdx.x;
    int rowBase = blockIdx.x * GTM;
    int rb = (t >> 4) << 3;         // 0,8,16,24
    int cb = (t & 15) << 3;         // 0..120
    float acc[8][8] = {};

    for (int kp = 0; kp < 128; kp += 32) {
        __syncthreads();
        {
            int r  = t >> 3;            // 0..7
            int c4 = (t & 7) << 2;      // 0..28
            #pragma unroll
            for (int i = 0; i < 4; ++i) {
                int gr = rowBase + r + i * 8;
                float4 v = (gr < n) ? *reinterpret_cast<const float4*>(A + (size_t)gr * D + kp + c4)
                                    : make_float4(0.f, 0.f, 0.f, 0.f);
                AsT[c4 + 0][r + i * 8] = v.x;
                AsT[c4 + 1][r + i * 8] = v.y;
                AsT[c4 + 2][r + i * 8] = v.z;
                AsT[c4 + 3][r + i * 8] = v.w;
            }
        }
        {
            int kk0 = t >> 5;           // 0..1
            int c4  = (t & 31) << 2;    // 0..124
            #pragma unroll
            for (int i = 0; i < 16; ++i) {
                int kk = kk0 + i * 2;
                *reinterpret_cast<float4*>(&Ws[kk][c4]) =
                    *reinterpret_cast<const float4*>(Wg + (size_t)(kp + kk) * D + c4);
            }
        }
        __syncthreads();

        #pragma unroll 8
        for (int kk = 0; kk < 32; ++kk) {
            float4 a0 = *reinterpret_cast<const float4*>(&AsT[kk][rb]);
            float4 a1 = *reinterpret_cast<const float4*>(&AsT[kk][rb + 4]);
            float4 w0 = *reinterpret_cast<const float4*>(&Ws[kk][cb]);
            float4 w1 = *reinterpret_cast<const float4*>(&Ws[kk][cb + 4]);
            float a[8] = {a0.x, a0.y, a0.z, a0.w, a1.x, a1.y, a1.z, a1.w};
            float w[8] = {w0.x, w0.y, w0.z, w0.w, w1.x, w1.y, w1.z, w1.w};
            #pragma unroll
            for (int r = 0; r < 8; ++r) {
                #pragma unroll
                for (int c = 0; c < 8; ++c) acc[r][c] += a[r] * w[c];
            }
        }
    }

    #pragma unroll
    for (int r = 0; r < 8; ++r) {
        int gr = rowBase + rb + r;
        if (gr < n) {
            float s = dinv[gr];
            float4 o0, o1;
            o0.x = acc[r][0] * s; o0.y = acc[r][1] * s; o0.z = acc[r][2] * s; o0.w = acc[r][3] * s;
            o1.x = acc[r][4] * s; o1.y = acc[r][5] * s; o1.z = acc[r][6] * s; o1.w = acc[r][7] * s;
            float* o = outp + (size_t)gr * D + cb;
            *reinterpret_cast<float4*>(o)     = o0;
            *reinterpret_cast<float4*>(o + 4) = o1;
        }
    }
}

// ---------------- aggregation (+ optional fused fc head) ----------------
// xws rows pre-scaled by dinv[row]:
//   h[d] = relu( dinv[d] * (sum_{e:s->d} xws[s] + xws[d]) + b )
// Indices preloaded lane-parallel, distributed by shuffle -> 4 gathers in
// flight per half-wave (no dependent csr_src load in the loop).
__global__ __launch_bounds__(256) void agg_kernel(const float* __restrict__ xws,
                                                  const int* __restrict__ csr_src,
                                                  const int* __restrict__ offsets,
                                                  const int* __restrict__ deg,
                                                  const float* __restrict__ dinv,
                                                  const float* __restrict__ bias,
                                                  float* __restrict__ outp,
                                                  const float* __restrict__ fcw,
                                                  const float* __restrict__ fcb,
                                                  float* __restrict__ fcout,
                                                  int n) {
    int wave = (blockIdx.x * blockDim.x + threadIdx.x) >> 6;
    int lane = threadIdx.x & 63;
    if (wave >= n) return;
    int node = wave;
    int half = lane >> 5;
    int l32  = lane & 31;
    size_t col = (size_t)(l32 << 2);

    int base = offsets[node];
    int cnt  = deg[node];

    // hoisted independent loads
    float di = dinv[node];
    float4 vs = *reinterpret_cast<const float4*>(xws + (size_t)node * D + col);
    float4 b  = *reinterpret_cast<const float4*>(bias + col);

    float4 acc0 = make_float4(0.f, 0.f, 0.f, 0.f);
    float4 acc1 = make_float4(0.f, 0.f, 0.f, 0.f);
    float4 acc2 = make_float4(0.f, 0.f, 0.f, 0.f);
    float4 acc3 = make_float4(0.f, 0.f, 0.f, 0.f);

    if (cnt <= 64) {
        int idx = (lane < cnt) ? csr_src[base + lane] : 0;
        int j = 0;
        for (; j + 8 <= cnt; j += 8) {
            int s0 = __shfl(idx, j     + half);
            int s1 = __shfl(idx, j + 2 + half);
            int s2 = __shfl(idx, j + 4 + half);
            int s3 = __shfl(idx, j + 6 + half);
            float4 v0 = *reinterpret_cast<const float4*>(xws + (size_t)s0 * D + col);
            float4 v1 = *reinterpret_cast<const float4*>(xws + (size_t)s1 * D + col);
            float4 v2 = *reinterpret_cast<const float4*>(xws + (size_t)s2 * D + col);
            float4 v3 = *reinterpret_cast<const float4*>(xws + (size_t)s3 * D + col);
            acc0.x += v0.x; acc0.y += v0.y; acc0.z += v0.z; acc0.w += v0.w;
            acc1.x += v1.x; acc1.y += v1.y; acc1.z += v1.z; acc1.w += v1.w;
            acc2.x += v2.x; acc2.y += v2.y; acc2.z += v2.z; acc2.w += v2.w;
            acc3.x += v3.x; acc3.y += v3.y; acc3.z += v3.z; acc3.w += v3.w;
        }
        for (; j + 2 <= cnt; j += 2) {
            int s0 = __shfl(idx, j + half);
            float4 v0 = *reinterpret_cast<const float4*>(xws + (size_t)s0 * D + col);
            acc0.x += v0.x; acc0.y += v0.y; acc0.z += v0.z; acc0.w += v0.w;
        }
        if (j < cnt) {
            int s0 = __shfl(idx, j);
            if (half == 0) {
                float4 v0 = *reinterpret_cast<const float4*>(xws + (size_t)s0 * D + col);
                acc1.x += v0.x; acc1.y += v0.y; acc1.z += v0.z; acc1.w += v0.w;
            }
        }
    } else {
        // fallback (essentially never taken for Poisson(16) degrees)
        int j = 0;
        for (; j + 2 <= cnt; j += 2) {
            int s = csr_src[base + j + half];
            float4 v = *reinterpret_cast<const float4*>(xws + (size_t)s * D + col);
            acc0.x += v.x; acc0.y += v.y; acc0.z += v.z; acc0.w += v.w;
        }
        if (j < cnt && half == 0) {
            int s = csr_src[base + j];
            float4 v = *reinterpret_cast<const float4*>(xws + (size_t)s * D + col);
            acc1.x += v.x; acc1.y += v.y; acc1.z += v.z; acc1.w += v.w;
        }
    }

    acc0.x += acc1.x + acc2.x + acc3.x;
    acc0.y += acc1.y + acc2.y + acc3.y;
    acc0.z += acc1.z + acc2.z + acc3.z;
    acc0.w += acc1.w + acc2.w + acc3.w;
    acc0.x += __shfl_down(acc0.x, 32);
    acc0.y += __shfl_down(acc0.y, 32);
    acc0.z += __shfl_down(acc0.z, 32);
    acc0.w += __shfl_down(acc0.w, 32);

    float4 r;
    r.x = fmaxf(di * (acc0.x + vs.x) + b.x, 0.f);
    r.y = fmaxf(di * (acc0.y + vs.y) + b.y, 0.f);
    r.z = fmaxf(di * (acc0.z + vs.z) + b.z, 0.f);
    r.w = fmaxf(di * (acc0.w + vs.w) + b.w, 0.f);

    if (fcw == nullptr) {
        if (half == 0)
            *reinterpret_cast<float4*>(outp + (size_t)node * D + col) = r;
    } else {
        float4 wv = *reinterpret_cast<const float4*>(fcw + col);
        float s = (half == 0) ? (r.x * wv.x + r.y * wv.y + r.z * wv.z + r.w * wv.w) : 0.f;
        #pragma unroll
        for (int off = 32; off > 0; off >>= 1) s += __shfl_down(s, off);
        if (lane == 0) fcout[node] = s + fcb[0];
    }
}

// ---------------- launch ----------------

extern "C" void kernel_launch(void* const* d_in, const int* in_sizes, int n_in,
                              void* d_out, int out_size, void* d_ws, size_t ws_size,
                              hipStream_t stream) {
    const float* x   = (const float*)d_in[0];
    const int*   ei  = (const int*)d_in[1];
    const float* W1  = (const float*)d_in[2];
    const float* b1  = (const float*)d_in[3];
    const float* W2  = (const float*)d_in[4];
    const float* b2  = (const float*)d_in[5];
    const float* W3  = (const float*)d_in[6];
    const float* b3  = (const float*)d_in[7];
    const float* Wfc = (const float*)d_in[8];
    const float* bfc = (const float*)d_in[9];
    float* outp = (float*)d_out;

    const int n = in_sizes[0] / D;        // 50000
    const int e = in_sizes[1] / 2;        // 800000
    const int* src = ei;
    const int* dst = ei + e;

    char* ws = (char*)d_ws;
    size_t off = 0;
    auto alloc = [&](size_t bytes) {
        void* p = ws + off;
        off += (bytes + 255) & ~(size_t)255;
        return p;
    };
    int*   deg     = (int*)alloc((size_t)n * 4);
    int*   cursor  = (int*)alloc((size_t)n * 4);
    size_t zero_bytes = off;              // deg + cursor zeroed
    int*   offsets = (int*)alloc((size_t)n * 4);
    float* dinv    = (float*)alloc((size_t)n * 4);
    int*   blkSums = (int*)alloc(64 * 4);
    int*   blkOff  = (int*)alloc(64 * 4);
    int*   csr_src = (int*)alloc((size_t)e * 4);
    float* buf0    = (float*)alloc((size_t)n * D * 4);
    float* buf1    = (float*)alloc((size_t)n * D * 4);

    int eb256 = (e + 255) / 256;
    int scan_blocks = (n + SCAN_ELEMS - 1) / SCAN_ELEMS;   // 13 (<=64)

    hipMemsetAsync(ws, 0, zero_bytes, stream);
    count_kernel<<<eb256, 256, 0, stream>>>(dst, deg, e);
    scanA_kernel<<<scan_blocks, 256, 0, stream>>>(deg, blkSums, n);
    scanB_kernel<<<1, 64, 0, stream>>>(blkSums, blkOff, scan_blocks);
    scanC_kernel<<<scan_blocks, 256, 0, stream>>>(deg, blkOff, offsets, dinv, n);
    fill_kernel <<<eb256, 256, 0, stream>>>(src, dst, offsets, cursor, csr_src, e);

    int gemm_blocks = (n + GTM - 1) / GTM;   // 1563
    int agg_blocks  = (n + 3) / 4;

    gemm_kernel<<<gemm_blocks, 64, 0, stream>>>(x, W1, dinv, buf0, n);
    agg_kernel <<<agg_blocks, 256, 0, stream>>>(buf0, csr_src, offsets, deg, dinv, b1, buf1,
                                                nullptr, nullptr, nullptr, n);
    gemm_kernel<<<gemm_blocks, 64, 0, stream>>>(buf1, W2, dinv, buf0, n);
    agg_kernel <<<agg_blocks, 256, 0, stream>>>(buf0, csr_src, offsets, deg, dinv, b2, buf1,
                                                nullptr, nullptr, nullptr, n);
    gemm_kernel<<<gemm_blocks, 64, 0, stream>>>(buf1, W3, dinv, buf0, n);
    agg_kernel <<<agg_blocks, 256, 0, stream>>>(buf0, csr_src, offsets, deg, dinv, b3, nullptr,
                                                Wfc, bfc, outp, n);
}

// Round 5
// 407.773 us; speedup vs baseline: 1.0801x; 1.0801x over previous
//
#include <hip/hip_runtime.h>

#define D 128
#define SCAN_ELEMS 4096   // elements per scan block (256 threads x 16)

// ---------------- precompute kernels ----------------
// deg[] counts REAL edges only (self-loop handled as +1 at use sites).
// count also records each edge's arrival rank within its dst bucket.

__global__ void count_kernel(const int* __restrict__ dst, int* __restrict__ deg,
                             int* __restrict__ rank, int e) {
    int i = blockIdx.x * blockDim.x + threadIdx.x;
    if (i < e) rank[i] = atomicAdd(&deg[dst[i]], 1);
}

// ---- hierarchical scan: A) block sums  B) scan block sums  C) final offsets + dinv ----

__global__ __launch_bounds__(256) void scanA_kernel(const int* __restrict__ deg,
                                                    int* __restrict__ blkSums, int n) {
    __shared__ int waveSums[4];
    int t = threadIdx.x;
    int base = blockIdx.x * SCAN_ELEMS + t * 16;
    int s = 0;
    if (base + 16 <= n) {
        const int4* p = reinterpret_cast<const int4*>(deg + base);
        #pragma unroll
        for (int k = 0; k < 4; ++k) {
            int4 v = p[k];
            s += v.x + v.y + v.z + v.w;
        }
    } else {
        for (int k = 0; k < 16; ++k) {
            int i = base + k;
            if (i < n) s += deg[i];
        }
    }
    #pragma unroll
    for (int off = 32; off > 0; off >>= 1) s += __shfl_down(s, off);
    int lane = t & 63, w = t >> 6;
    if (lane == 0) waveSums[w] = s;
    __syncthreads();
    if (t == 0) blkSums[blockIdx.x] = waveSums[0] + waveSums[1] + waveSums[2] + waveSums[3];
}

__global__ void scanB_kernel(const int* __restrict__ blkSums, int* __restrict__ blkOff, int nblk) {
    int t = threadIdx.x;   // 64 threads
    int s = (t < nblk) ? blkSums[t] : 0;
    int orig = s;
    #pragma unroll
    for (int off = 1; off < 64; off <<= 1) {
        int u = __shfl_up(s, off);
        if (t >= off) s += u;
    }
    if (t < nblk) blkOff[t] = s - orig;   // exclusive
}

__global__ __launch_bounds__(256) void scanC_kernel(const int* __restrict__ deg,
                                                    const int* __restrict__ blkOff,
                                                    int* __restrict__ offsets,
                                                    float* __restrict__ dinv, int n) {
    __shared__ int waveSums[4];
    int t = threadIdx.x;
    int lane = t & 63, w = t >> 6;
    int base = blockIdx.x * SCAN_ELEMS + t * 16;

    int v[16];
    int s = 0;
    #pragma unroll
    for (int k = 0; k < 16; ++k) {
        int i = base + k;
        int d = (i < n) ? deg[i] : 0;
        v[k] = d;
        s += d;
    }
    int incl = s;
    #pragma unroll
    for (int off = 1; off < 64; off <<= 1) {
        int u = __shfl_up(incl, off);
        if (lane >= off) incl += u;
    }
    if (lane == 63) waveSums[w] = incl;
    __syncthreads();
    int waveOff = 0;
    for (int i = 0; i < 4; ++i) if (i < w) waveOff += waveSums[i];
    int off0 = blkOff[blockIdx.x] + waveOff + incl - s;

    #pragma unroll
    for (int k = 0; k < 16; ++k) {
        int i = base + k;
        if (i < n) {
            offsets[i] = off0;
            dinv[i] = rsqrtf((float)(v[k] + 1));   // +1 self-loop
            off0 += v[k];
        }
    }
}

__global__ void fill_kernel(const int* __restrict__ src, const int* __restrict__ dst,
                            const int* __restrict__ offsets, const int* __restrict__ rank,
                            int* __restrict__ csr_src, int e) {
    int i = blockIdx.x * blockDim.x + threadIdx.x;
    if (i < e) {
        csr_src[offsets[dst[i]] + rank[i]] = src[i];
    }
}

// ---------------- dense transform: out[r][c] = dinv[r] * (A[r][:] @ W[:][c]) ----------------
// 256 threads, 64 rows/block, BK=32, thread tile 8 rows x 4 cols.
// LDS = AsT 32*68*4 (8.5KB) + Ws 32*132*4 (16.9KB) = 25.4KB -> 6 blocks/CU (24 waves).
__global__ __launch_bounds__(256, 6) void gemm_kernel(const float* __restrict__ A,
                                                      const float* __restrict__ Wg,
                                                      const float* __restrict__ dinv,
                                                      float* __restrict__ outp, int n) {
    __shared__ float AsT[32][68];   // [k][row], 272B row stride (16B aligned)
    __shared__ float Ws[32][132];   // [k][col]

    int t = threadIdx.x;
    int rowBase = blockIdx.x * 64;
    int rb = (t >> 5) << 3;         // 0,8,...,56
    int cb = (t & 31) << 2;         // 0..124
    float acc[8][4] = {};

    for (int kp = 0; kp < 128; kp += 32) {
        __syncthreads();
        // stage A (64 rows x 32 k), transposed into AsT[k][row]
        {
            int r0 = t >> 3;            // 0..31
            int c4 = (t & 7) << 2;      // 0..28
            #pragma unroll
            for (int it = 0; it < 2; ++it) {
                int r = r0 + it * 32;
                int gr = rowBase + r;
                float4 v = (gr < n) ? *reinterpret_cast<const float4*>(A + (size_t)gr * D + kp + c4)
                                    : make_float4(0.f, 0.f, 0.f, 0.f);
                AsT[c4 + 0][r] = v.x;
                AsT[c4 + 1][r] = v.y;
                AsT[c4 + 2][r] = v.z;
                AsT[c4 + 3][r] = v.w;
            }
        }
        // stage W (32 k x 128 cols)
        {
            int kk0 = t >> 5;           // 0..7
            int c4  = (t & 31) << 2;    // 0..124
            #pragma unroll
            for (int it = 0; it < 4; ++it) {
                int kk = kk0 + it * 8;
                *reinterpret_cast<float4*>(&Ws[kk][c4]) =
                    *reinterpret_cast<const float4*>(Wg + (size_t)(kp + kk) * D + c4);
            }
        }
        __syncthreads();

        #pragma unroll 8
        for (int kk = 0; kk < 32; ++kk) {
            float4 a0 = *reinterpret_cast<const float4*>(&AsT[kk][rb]);
            float4 a1 = *reinterpret_cast<const float4*>(&AsT[kk][rb + 4]);
            float4 w  = *reinterpret_cast<const float4*>(&Ws[kk][cb]);
            float a[8] = {a0.x, a0.y, a0.z, a0.w, a1.x, a1.y, a1.z, a1.w};
            #pragma unroll
            for (int r = 0; r < 8; ++r) {
                acc[r][0] += a[r] * w.x;
                acc[r][1] += a[r] * w.y;
                acc[r][2] += a[r] * w.z;
                acc[r][3] += a[r] * w.w;
            }
        }
    }

    #pragma unroll
    for (int r = 0; r < 8; ++r) {
        int gr = rowBase + rb + r;
        if (gr < n) {
            float s = dinv[gr];
            float4 o;
            o.x = acc[r][0] * s; o.y = acc[r][1] * s;
            o.z = acc[r][2] * s; o.w = acc[r][3] * s;
            *reinterpret_cast<float4*>(outp + (size_t)gr * D + cb) = o;
        }
    }
}

// ---------------- aggregation (+ optional fused fc head) ----------------
// xws rows pre-scaled by dinv[row]:
//   h[d] = relu( dinv[d] * (sum_{e:s->d} xws[s] + xws[d]) + b )
__global__ __launch_bounds__(256) void agg_kernel(const float* __restrict__ xws,
                                                  const int* __restrict__ csr_src,
                                                  const int* __restrict__ offsets,
                                                  const int* __restrict__ deg,
                                                  const float* __restrict__ dinv,
                                                  const float* __restrict__ bias,
                                                  float* __restrict__ outp,
                                                  const float* __restrict__ fcw,
                                                  const float* __restrict__ fcb,
                                                  float* __restrict__ fcout,
                                                  int n) {
    int wave = (blockIdx.x * blockDim.x + threadIdx.x) >> 6;
    int lane = threadIdx.x & 63;
    if (wave >= n) return;
    int node = wave;
    int half = lane >> 5;
    int l32  = lane & 31;
    size_t col = (size_t)(l32 << 2);

    int base = offsets[node];
    int cnt  = deg[node];

    float di = dinv[node];
    float4 vs = *reinterpret_cast<const float4*>(xws + (size_t)node * D + col);
    float4 b  = *reinterpret_cast<const float4*>(bias + col);

    float4 acc0 = make_float4(0.f, 0.f, 0.f, 0.f);
    float4 acc1 = make_float4(0.f, 0.f, 0.f, 0.f);
    float4 acc2 = make_float4(0.f, 0.f, 0.f, 0.f);
    float4 acc3 = make_float4(0.f, 0.f, 0.f, 0.f);

    if (cnt <= 64) {
        int idx = (lane < cnt) ? csr_src[base + lane] : 0;
        int j = 0;
        for (; j + 8 <= cnt; j += 8) {
            int s0 = __shfl(idx, j     + half);
            int s1 = __shfl(idx, j + 2 + half);
            int s2 = __shfl(idx, j + 4 + half);
            int s3 = __shfl(idx, j + 6 + half);
            float4 v0 = *reinterpret_cast<const float4*>(xws + (size_t)s0 * D + col);
            float4 v1 = *reinterpret_cast<const float4*>(xws + (size_t)s1 * D + col);
            float4 v2 = *reinterpret_cast<const float4*>(xws + (size_t)s2 * D + col);
            float4 v3 = *reinterpret_cast<const float4*>(xws + (size_t)s3 * D + col);
            acc0.x += v0.x; acc0.y += v0.y; acc0.z += v0.z; acc0.w += v0.w;
            acc1.x += v1.x; acc1.y += v1.y; acc1.z += v1.z; acc1.w += v1.w;
            acc2.x += v2.x; acc2.y += v2.y; acc2.z += v2.z; acc2.w += v2.w;
            acc3.x += v3.x; acc3.y += v3.y; acc3.z += v3.z; acc3.w += v3.w;
        }
        for (; j + 2 <= cnt; j += 2) {
            int s0 = __shfl(idx, j + half);
            float4 v0 = *reinterpret_cast<const float4*>(xws + (size_t)s0 * D + col);
            acc0.x += v0.x; acc0.y += v0.y; acc0.z += v0.z; acc0.w += v0.w;
        }
        if (j < cnt) {
            int s0 = __shfl(idx, j);
            if (half == 0) {
                float4 v0 = *reinterpret_cast<const float4*>(xws + (size_t)s0 * D + col);
                acc1.x += v0.x; acc1.y += v0.y; acc1.z += v0.z; acc1.w += v0.w;
            }
        }
    } else {
        int j = 0;
        for (; j + 2 <= cnt; j += 2) {
            int s = csr_src[base + j + half];
            float4 v = *reinterpret_cast<const float4*>(xws + (size_t)s * D + col);
            acc0.x += v.x; acc0.y += v.y; acc0.z += v.z; acc0.w += v.w;
        }
        if (j < cnt && half == 0) {
            int s = csr_src[base + j];
            float4 v = *reinterpret_cast<const float4*>(xws + (size_t)s * D + col);
            acc1.x += v.x; acc1.y += v.y; acc1.z += v.z; acc1.w += v.w;
        }
    }

    acc0.x += acc1.x + acc2.x + acc3.x;
    acc0.y += acc1.y + acc2.y + acc3.y;
    acc0.z += acc1.z + acc2.z + acc3.z;
    acc0.w += acc1.w + acc2.w + acc3.w;
    acc0.x += __shfl_down(acc0.x, 32);
    acc0.y += __shfl_down(acc0.y, 32);
    acc0.z += __shfl_down(acc0.z, 32);
    acc0.w += __shfl_down(acc0.w, 32);

    float4 r;
    r.x = fmaxf(di * (acc0.x + vs.x) + b.x, 0.f);
    r.y = fmaxf(di * (acc0.y + vs.y) + b.y, 0.f);
    r.z = fmaxf(di * (acc0.z + vs.z) + b.z, 0.f);
    r.w = fmaxf(di * (acc0.w + vs.w) + b.w, 0.f);

    if (fcw == nullptr) {
        if (half == 0)
            *reinterpret_cast<float4*>(outp + (size_t)node * D + col) = r;
    } else {
        float4 wv = *reinterpret_cast<const float4*>(fcw + col);
        float s = (half == 0) ? (r.x * wv.x + r.y * wv.y + r.z * wv.z + r.w * wv.w) : 0.f;
        #pragma unroll
        for (int off = 32; off > 0; off >>= 1) s += __shfl_down(s, off);
        if (lane == 0) fcout[node] = s + fcb[0];
    }
}

// ---------------- launch ----------------

extern "C" void kernel_launch(void* const* d_in, const int* in_sizes, int n_in,
                              void* d_out, int out_size, void* d_ws, size_t ws_size,
                              hipStream_t stream) {
    const float* x   = (const float*)d_in[0];
    const int*   ei  = (const int*)d_in[1];
    const float* W1  = (const float*)d_in[2];
    const float* b1  = (const float*)d_in[3];
    const float* W2  = (const float*)d_in[4];
    const float* b2  = (const float*)d_in[5];
    const float* W3  = (const float*)d_in[6];
    const float* b3  = (const float*)d_in[7];
    const float* Wfc = (const float*)d_in[8];
    const float* bfc = (const float*)d_in[9];
    float* outp = (float*)d_out;

    const int n = in_sizes[0] / D;        // 50000
    const int e = in_sizes[1] / 2;        // 800000
    const int* src = ei;
    const int* dst = ei + e;

    char* ws = (char*)d_ws;
    size_t off = 0;
    auto alloc = [&](size_t bytes) {
        void* p = ws + off;
        off += (bytes + 255) & ~(size_t)255;
        return p;
    };
    int*   deg     = (int*)alloc((size_t)n * 4);
    size_t zero_bytes = off;              // deg zeroed
    int*   offsets = (int*)alloc((size_t)n * 4);
    float* dinv    = (float*)alloc((size_t)n * 4);
    int*   blkSums = (int*)alloc(64 * 4);
    int*   blkOff  = (int*)alloc(64 * 4);
    int*   rank    = (int*)alloc((size_t)e * 4);
    int*   csr_src = (int*)alloc((size_t)e * 4);
    float* buf0    = (float*)alloc((size_t)n * D * 4);
    float* buf1    = (float*)alloc((size_t)n * D * 4);

    int eb256 = (e + 255) / 256;
    int scan_blocks = (n + SCAN_ELEMS - 1) / SCAN_ELEMS;   // 13 (<=64)

    hipMemsetAsync(ws, 0, zero_bytes, stream);
    count_kernel<<<eb256, 256, 0, stream>>>(dst, deg, rank, e);
    scanA_kernel<<<scan_blocks, 256, 0, stream>>>(deg, blkSums, n);
    scanB_kernel<<<1, 64, 0, stream>>>(blkSums, blkOff, scan_blocks);
    scanC_kernel<<<scan_blocks, 256, 0, stream>>>(deg, blkOff, offsets, dinv, n);
    fill_kernel <<<eb256, 256, 0, stream>>>(src, dst, offsets, rank, csr_src, e);

    int gemm_blocks = (n + 63) / 64;      // 782
    int agg_blocks  = (n + 3) / 4;

    gemm_kernel<<<gemm_blocks, 256, 0, stream>>>(x, W1, dinv, buf0, n);
    agg_kernel <<<agg_blocks, 256, 0, stream>>>(buf0, csr_src, offsets, deg, dinv, b1, buf1,
                                                nullptr, nullptr, nullptr, n);
    gemm_kernel<<<gemm_blocks, 256, 0, stream>>>(buf1, W2, dinv, buf0, n);
    agg_kernel <<<agg_blocks, 256, 0, stream>>>(buf0, csr_src, offsets, deg, dinv, b2, buf1,
                                                nullptr, nullptr, nullptr, n);
    gemm_kernel<<<gemm_blocks, 256, 0, stream>>>(buf1, W3, dinv, buf0, n);
    agg_kernel <<<agg_blocks, 256, 0, stream>>>(buf0, csr_src, offsets, deg, dinv, b3, nullptr,
                                                Wfc, bfc, outp, n);
}